// Round 8
// baseline (80.313 us; speedup 1.0000x reference)
//
#include <hip/hip_runtime.h>
#include <math.h>

#define LSEQ 512
#define DMODEL 512
#define DT 64
#define DFF 2048

typedef unsigned short u16;
typedef __attribute__((ext_vector_type(8))) short short8;
typedef __attribute__((ext_vector_type(4))) float f32x4;
typedef __attribute__((ext_vector_type(16))) float f32x16;

__device__ __forceinline__ float wave_sum(float v) {
#pragma unroll
  for (int o = 32; o > 0; o >>= 1) v += __shfl_xor(v, o, 64);
  return v;
}

__device__ __forceinline__ u16 f2bf(float f) {
  unsigned int u = __float_as_uint(f);
  u += 0x7fffu + ((u >> 16) & 1u);
  return (u16)(u >> 16);
}
__device__ __forceinline__ float bf2f(u16 h) {
  return __uint_as_float(((unsigned int)h) << 16);
}
__device__ __forceinline__ void splitbf(float f, u16& h, u16& l) {
  h = f2bf(f);
  l = f2bf(f - bf2f(h));
}

// ---------------- k_pre: weight cvt (w1,w2 plain bf16; small weights hi+lo) + LN1 ----
// float4-unit weight regions: w1[0,262144) w2[..524288) fcw[..532480) liw[..540672)
//                             wa[..542720) low[..550912).  Blocks >= 2152: LN1.
__global__ __launch_bounds__(256) void k_pre(
    const float* __restrict__ w1, const float* __restrict__ w2,
    const float* __restrict__ fcw, const float* __restrict__ liw,
    const float* __restrict__ wa, const float* __restrict__ low,
    const float* __restrict__ x, const float* __restrict__ g1,
    const float* __restrict__ be1,
    u16* __restrict__ w1b, u16* __restrict__ w2b,
    u16* __restrict__ fclh, u16* __restrict__ fcll,
    u16* __restrict__ wah, u16* __restrict__ wal,
    u16* __restrict__ lowh, u16* __restrict__ lowl,
    u16* __restrict__ xnh, u16* __restrict__ xnl)
{
  if (blockIdx.x >= 2152) {                  // ---- LN1: 256 blocks x 4 rows ----
    const int lane = threadIdx.x & 63, wv = threadIdx.x >> 6;
    const int row = (blockIdx.x - 2152) * 4 + wv;
    const float* xr = x + (size_t)row * DMODEL;
    float v[8]; float s = 0.f;
#pragma unroll
    for (int j = 0; j < 8; ++j) { v[j] = xr[lane + 64 * j]; s += v[j]; }
    s = wave_sum(s);
    const float mu = s * (1.f / 512.f);
    float q = 0.f;
#pragma unroll
    for (int j = 0; j < 8; ++j) { float dd = v[j] - mu; q += dd * dd; }
    q = wave_sum(q);
    const float rstd = rsqrtf(q * (1.f / 512.f) + 1e-5f);
#pragma unroll
    for (int j = 0; j < 8; ++j) {
      int idx = lane + 64 * j;
      float o = (v[j] - mu) * rstd * g1[idx] + be1[idx];
      u16 h, l; splitbf(o, h, l);
      xnh[(size_t)row * DMODEL + idx] = h;
      xnl[(size_t)row * DMODEL + idx] = l;
    }
    return;
  }
  int i = blockIdx.x * 256 + threadIdx.x;
  if (i >= 550912) return;
  if (i < 524288) {                          // w1 / w2: plain bf16
    const float* s = (i < 262144) ? w1 : w2;
    u16* d = (i < 262144) ? w1b : w2b;
    int off = (i < 262144) ? i : i - 262144;
    float4 v = ((const float4*)s)[off];
    ushort4 o;
    o.x = f2bf(v.x); o.y = f2bf(v.y); o.z = f2bf(v.z); o.w = f2bf(v.w);
    ((ushort4*)d)[off] = o;
    return;
  }
  const float* s; int j; u16 *dh, *dl;
  if (i < 532480)      { s = fcw; j = i - 524288;        dh = fclh; dl = fcll; }
  else if (i < 540672) { s = liw; j = i - 532480 + 8192; dh = fclh; dl = fcll; }
  else if (i < 542720) { s = wa;  j = i - 540672;        dh = wah;  dl = wal;  }
  else                 { s = low; j = i - 542720;        dh = lowh; dl = lowl; }
  int soff = (i < 532480) ? i - 524288 :
             (i < 540672) ? i - 532480 :
             (i < 542720) ? i - 540672 : i - 542720;
  float4 v = ((const float4*)s)[soff];
  ushort4 oh, ol;
  splitbf(v.x, oh.x, ol.x); splitbf(v.y, oh.y, ol.y);
  splitbf(v.z, oh.z, ol.z); splitbf(v.w, oh.w, ol.w);
  ((ushort4*)dh)[j] = oh;
  ((ushort4*)dl)[j] = ol;
}

// ---------------- k_fa: fused proj(fc+lin_in, bf16x3) + au GEMM + a-map --------------
// 64 blocks x 512 thr (8 waves). Phase1: wave w -> proj col-tile w (c = w*16+lr).
// u (cols 64..127) lands in LDS hi/lo; Phase2: wave w -> au col-tile w (N=128).
__global__ __launch_bounds__(512) void k_fa(
    const u16* __restrict__ xnh, const u16* __restrict__ xnl,
    const u16* __restrict__ fclh, const u16* __restrict__ fcll,
    const u16* __restrict__ wah, const u16* __restrict__ wal,
    const float* __restrict__ fcb, const float* __restrict__ lib,
    float* __restrict__ y_o, float* __restrict__ u_o,
    float* __restrict__ ar_o, float* __restrict__ ai_o)
{
  __shared__ __align__(16) u16 ush[16][80];
  __shared__ __align__(16) u16 usl[16][80];
  const int w = threadIdx.x >> 6, lane = threadIdx.x & 63;
  const int mt = blockIdx.x;
  const int lr = lane & 15, lk = lane >> 4;

  {  // phase 1: proj tile, K=512, bf16x3
    const size_t aoff = (size_t)(mt * 16 + lr) * DMODEL + lk * 8;
    const size_t boff = (size_t)(w * 16 + lr) * DMODEL + lk * 8;
    f32x4 acc = {};
#pragma unroll 4
    for (int k = 0; k < DMODEL; k += 32) {
      short8 ah = *(const short8*)(xnh + aoff + k);
      short8 al = *(const short8*)(xnl + aoff + k);
      short8 bh = *(const short8*)(fclh + boff + k);
      short8 bl = *(const short8*)(fcll + boff + k);
      acc = __builtin_amdgcn_mfma_f32_16x16x32_bf16(ah, bh, acc, 0, 0, 0);
      acc = __builtin_amdgcn_mfma_f32_16x16x32_bf16(ah, bl, acc, 0, 0, 0);
      acc = __builtin_amdgcn_mfma_f32_16x16x32_bf16(al, bh, acc, 0, 0, 0);
    }
    const int c = w * 16 + lr;
#pragma unroll
    for (int j = 0; j < 4; ++j) {
      int rl = lk * 4 + j;
      int row = mt * 16 + rl;
      float v = acc[j];
      if (c < DT) {
        v += fcb[c];
        y_o[row * DT + c] = v / (1.f + expf(-v));        // silu gate (fp32)
      } else {
        int d = c - DT;
        v += lib[d];
        u_o[row * DT + d] = v;                           // fp32 for scan
        u16 h, l; splitbf(v, h, l);
        ush[rl][d] = h; usl[rl][d] = l;
      }
    }
  }
  __syncthreads();
  {  // phase 2: au tile nt=w over K=64, bf16x3; then a-map
    const size_t boff = (size_t)(w * 16 + lr) * DT + lk * 8;
    f32x4 acc = {};
#pragma unroll
    for (int ks = 0; ks < 2; ++ks) {
      short8 ah = *(const short8*)&ush[lr][ks * 32 + lk * 8];
      short8 al = *(const short8*)&usl[lr][ks * 32 + lk * 8];
      short8 bh = *(const short8*)(wah + boff + ks * 32);
      short8 bl = *(const short8*)(wal + boff + ks * 32);
      acc = __builtin_amdgcn_mfma_f32_16x16x32_bf16(ah, bh, acc, 0, 0, 0);
      acc = __builtin_amdgcn_mfma_f32_16x16x32_bf16(ah, bl, acc, 0, 0, 0);
      acc = __builtin_amdgcn_mfma_f32_16x16x32_bf16(al, bh, acc, 0, 0, 0);
    }
    const int c = w * 16 + lr;
#pragma unroll
    for (int j = 0; j < 4; ++j) {
      float v = acc[j];
      float p = __shfl_xor(v, 1, 64);
      float re = (lane & 1) ? p : v;
      float im = (lane & 1) ? v : p;
      float asq = re * re + im * im;
      float sc = rsqrtf(asq) * expf(-asq);
      int row = mt * 16 + lk * 4 + j;
      int d = c >> 1;
      if (lane & 1) ai_o[row * DT + d] = im * sc;
      else          ar_o[row * DT + d] = re * sc;
    }
  }
}

// ---------------- parallel backward affine scan (unchanged) --------------------------
__global__ __launch_bounds__(64) void k_scan2(
    const float* __restrict__ u, const float* __restrict__ ar, const float* __restrict__ ai,
    const float* __restrict__ hr, const float* __restrict__ hi, float* __restrict__ h_o)
{
  const int blk = blockIdx.x;             // 0..127
  const int b = blk >> 6, d = blk & 63;
  const int lane = threadIdx.x;           // 0..63
  const size_t base = (size_t)b * LSEQ * DT + d;
  const int i0 = lane * 8;

  float a_r[8], a_i[8], b_r[8], b_i[8];
#pragma unroll
  for (int e = 0; e < 8; ++e) {
    int i = i0 + e;
    a_r[e] = ar[base + (size_t)i * DT];
    a_i[e] = ai[base + (size_t)i * DT];
    if (i >= 2)      { b_r[e] = u[base + (size_t)(i - 2) * DT]; b_i[e] = 0.f; }
    else if (i == 1) { b_r[e] = hr[d]; b_i[e] = hi[d]; }
    else             { b_r[e] = 0.f;   b_i[e] = 0.f; }
  }

  float Ar = 1.f, Ai = 0.f, Br = 0.f, Bi = 0.f;
#pragma unroll
  for (int e = 0; e < 8; ++e) {
    float nBr = fmaf(Ar, b_r[e], fmaf(-Ai, b_i[e], Br));
    float nBi = fmaf(Ar, b_i[e], fmaf( Ai, b_r[e], Bi));
    float nAr = Ar * a_r[e] - Ai * a_i[e];
    float nAi = Ar * a_i[e] + Ai * a_r[e];
    Ar = nAr; Ai = nAi; Br = nBr; Bi = nBi;
  }

#pragma unroll
  for (int dlt = 1; dlt < 64; dlt <<= 1) {
    float Ar2 = __shfl_down(Ar, dlt, 64);
    float Ai2 = __shfl_down(Ai, dlt, 64);
    float Br2 = __shfl_down(Br, dlt, 64);
    float Bi2 = __shfl_down(Bi, dlt, 64);
    if (lane + dlt < 64) {
      float nAr = Ar * Ar2 - Ai * Ai2;
      float nAi = Ar * Ai2 + Ai * Ar2;
      float nBr = fmaf(Ar, Br2, fmaf(-Ai, Bi2, Br));
      float nBi = fmaf(Ar, Bi2, fmaf( Ai, Br2, Bi));
      Ar = nAr; Ai = nAi; Br = nBr; Bi = nBi;
    }
  }

  float A1r = __shfl_down(Ar, 1, 64), A1i = __shfl_down(Ai, 1, 64);
  float B1r = __shfl_down(Br, 1, 64), B1i = __shfl_down(Bi, 1, 64);
  if (lane == 63) { A1r = 1.f; A1i = 0.f; B1r = 0.f; B1i = 0.f; }
  const float r512 = u[base + (size_t)(LSEQ - 2) * DT];
  float rr = fmaf(A1r, r512, B1r);
  float ri = fmaf(A1i, r512, B1i);

  const float uL = u[base + (size_t)(LSEQ - 1) * DT];
#pragma unroll
  for (int e = 7; e >= 0; --e) {
    int i = i0 + e;
    float nr = fmaf(a_r[e], rr, fmaf(-a_i[e], ri, b_r[e]));
    float ni = fmaf(a_r[e], ri, fmaf( a_i[e], rr, b_i[e]));
    rr = nr; ri = ni;
    float outv = rr;
    if (i == LSEQ - 1) outv += uL;
    h_o[base + (size_t)i * DT] = outv;
  }
}

// ---------------- k_midln: x2 = (h*y)@low^T+lob+x (bf16x3) then LN2 -> bf16 ----------
// 64 blocks x 512 thr. Phase0: hy -> LDS hi/lo. Phase1: 4 col-tiles per wave.
// Phase2: LN2 from x2s LDS.
__global__ __launch_bounds__(512) void k_midln(
    const float* __restrict__ h, const float* __restrict__ y,
    const u16* __restrict__ lowh, const u16* __restrict__ lowl,
    const float* __restrict__ lob, const float* __restrict__ x,
    const float* __restrict__ g2, const float* __restrict__ be2,
    float* __restrict__ x2_o, u16* __restrict__ xn2b)
{
  __shared__ __align__(16) u16 hyh[16][80];
  __shared__ __align__(16) u16 hyl[16][80];
  __shared__ float x2s[16][520];
  const int tid = threadIdx.x;
  const int w = tid >> 6, lane = tid & 63;
  const int lr = lane & 15, lk = lane >> 4;
  const int mt = blockIdx.x;

  for (int s = tid; s < 16 * DT; s += 512) {   // phase 0: hy hi/lo
    int r = s >> 6, d = s & 63;
    int row = mt * 16 + r;
    float v = h[row * DT + d] * y[row * DT + d];
    u16 hh, ll; splitbf(v, hh, ll);
    hyh[r][d] = hh; hyl[r][d] = ll;
  }
  __syncthreads();

#pragma unroll
  for (int t = 0; t < 4; ++t) {                // phase 1: tiles nt = w*4+t
    const int nt = w * 4 + t;
    const size_t boff = (size_t)(nt * 16 + lr) * DT + lk * 8;
    f32x4 acc = {};
#pragma unroll
    for (int ks = 0; ks < 2; ++ks) {
      short8 ah = *(const short8*)&hyh[lr][ks * 32 + lk * 8];
      short8 al = *(const short8*)&hyl[lr][ks * 32 + lk * 8];
      short8 bh = *(const short8*)(lowh + boff + ks * 32);
      short8 bl = *(const short8*)(lowl + boff + ks * 32);
      acc = __builtin_amdgcn_mfma_f32_16x16x32_bf16(ah, bh, acc, 0, 0, 0);
      acc = __builtin_amdgcn_mfma_f32_16x16x32_bf16(ah, bl, acc, 0, 0, 0);
      acc = __builtin_amdgcn_mfma_f32_16x16x32_bf16(al, bh, acc, 0, 0, 0);
    }
    const int c = nt * 16 + lr;
#pragma unroll
    for (int j = 0; j < 4; ++j) {
      int rl = lk * 4 + j;
      int row = mt * 16 + rl;
      float v = acc[j] + lob[c] + x[(size_t)row * DMODEL + c];
      x2s[rl][c] = v;
      x2_o[(size_t)row * DMODEL + c] = v;
    }
  }
  __syncthreads();

#pragma unroll
  for (int rr = 0; rr < 2; ++rr) {             // phase 2: LN2, 2 rows/wave
    const int r = w * 2 + rr;
    const int row = mt * 16 + r;
    float v[8]; float s = 0.f;
#pragma unroll
    for (int j = 0; j < 8; ++j) { v[j] = x2s[r][lane + 64 * j]; s += v[j]; }
    s = wave_sum(s);
    const float mu = s * (1.f / 512.f);
    float q = 0.f;
#pragma unroll
    for (int j = 0; j < 8; ++j) { float dd = v[j] - mu; q += dd * dd; }
    q = wave_sum(q);
    const float rstd = rsqrtf(q * (1.f / 512.f) + 1e-5f);
#pragma unroll
    for (int j = 0; j < 8; ++j) {
      int idx = lane + 64 * j;
      xn2b[(size_t)row * DMODEL + idx] = f2bf((v[j] - mu) * rstd * g2[idx] + be2[idx]);
    }
  }
}

// ---------------- k_ffn1: h1 = silu(xn2 @ w1^T + b1), wave-per-32x32 tile ------------
// grid (32,16) x 256 thr; wave w -> nt = by*4+w. No LDS, no barriers; L2-resident.
__global__ __launch_bounds__(256) void k_ffn1(
    const u16* __restrict__ A, const u16* __restrict__ B,
    const float* __restrict__ bias, u16* __restrict__ C)
{
  const int w = threadIdx.x >> 6, lane = threadIdx.x & 63;
  const int mt = blockIdx.x, nt = blockIdx.y * 4 + w;
  const int l32 = lane & 31, hi = lane >> 5;
  const u16* a = A + (size_t)(mt * 32 + l32) * DMODEL + hi * 8;
  const u16* b = B + (size_t)(nt * 32 + l32) * DMODEL + hi * 8;
  f32x16 acc = {};
#pragma unroll 8
  for (int k = 0; k < DMODEL; k += 16)
    acc = __builtin_amdgcn_mfma_f32_32x32x16_bf16(*(const short8*)(a + k),
                                                  *(const short8*)(b + k), acc, 0, 0, 0);
  const int col = nt * 32 + l32;
  const float bb = bias[col];
#pragma unroll
  for (int r = 0; r < 16; ++r) {
    int row = mt * 32 + (r & 3) + 8 * (r >> 2) + 4 * hi;
    float v = acc[r] + bb;
    v = v / (1.f + expf(-v));                            // silu
    C[(size_t)row * DFF + col] = f2bf(v);
  }
}

// ---------------- k_ffn2: out = h1 @ w2^T + b2 + x2; 4-wave in-block split-K ---------
// grid (32,16) x 256 thr; wave w does K quarter w; LDS reduce; fused epilogue.
__global__ __launch_bounds__(256) void k_ffn2(
    const u16* __restrict__ A, const u16* __restrict__ B,
    const float* __restrict__ b2, const float* __restrict__ x2,
    float* __restrict__ out)
{
  __shared__ float red[4][16][64];
  const int w = threadIdx.x >> 6, lane = threadIdx.x & 63;
  const int mt = blockIdx.x, nt = blockIdx.y;
  const int l32 = lane & 31, hi = lane >> 5;
  const u16* a = A + (size_t)(mt * 32 + l32) * DFF + w * 512 + hi * 8;
  const u16* b = B + (size_t)(nt * 32 + l32) * DFF + w * 512 + hi * 8;
  f32x16 acc = {};
#pragma unroll 8
  for (int k = 0; k < 512; k += 16)
    acc = __builtin_amdgcn_mfma_f32_32x32x16_bf16(*(const short8*)(a + k),
                                                  *(const short8*)(b + k), acc, 0, 0, 0);
#pragma unroll
  for (int r = 0; r < 16; ++r) red[w][r][lane] = acc[r];
  __syncthreads();
  for (int s = threadIdx.x; s < 1024; s += 256) {
    int r = s >> 6, l = s & 63;
    float v = red[0][r][l] + red[1][r][l] + red[2][r][l] + red[3][r][l];
    int row = mt * 32 + (r & 3) + 8 * (r >> 2) + 4 * (l >> 5);
    int col = nt * 32 + (l & 31);
    out[(size_t)row * DMODEL + col] =
        v + b2[col] + x2[(size_t)row * DMODEL + col];
  }
}

// ---------------- launch -------------------------------------------------------------
extern "C" void kernel_launch(void* const* d_in, const int* in_sizes, int n_in,
                              void* d_out, int out_size, void* d_ws, size_t ws_size,
                              hipStream_t stream) {
  const float* x    = (const float*)d_in[0];
  const float* ln1g = (const float*)d_in[1];
  const float* ln1b = (const float*)d_in[2];
  const float* fcw  = (const float*)d_in[3];
  const float* fcb  = (const float*)d_in[4];
  const float* liw  = (const float*)d_in[5];
  const float* lib  = (const float*)d_in[6];
  const float* wa   = (const float*)d_in[7];
  const float* hidr = (const float*)d_in[8];
  const float* hidi = (const float*)d_in[9];
  const float* low  = (const float*)d_in[10];
  const float* lob  = (const float*)d_in[11];
  const float* ln2g = (const float*)d_in[12];
  const float* ln2b = (const float*)d_in[13];
  const float* w1   = (const float*)d_in[14];
  const float* b1   = (const float*)d_in[15];
  const float* w2   = (const float*)d_in[16];
  const float* b2   = (const float*)d_in[17];
  float* out = (float*)d_out;
  float* ws  = (float*)d_ws;

  float* y_   = ws;                            // 65536
  float* u_   = y_  + 65536;
  float* ar_  = u_  + 65536;
  float* ai_  = ar_ + 65536;
  float* h_   = ai_ + 65536;
  float* x2_  = h_  + 65536;                   // 524288
  u16* p = (u16*)(x2_ + 524288);
  u16* xnh  = p;            p += 524288;
  u16* xnl  = p;            p += 524288;
  u16* xn2b = p;            p += 524288;
  u16* h1b  = p;            p += 2097152;
  u16* w1b  = p;            p += 1048576;
  u16* w2b  = p;            p += 1048576;
  u16* fclh = p;            p += 65536;
  u16* fcll = p;            p += 65536;
  u16* wah  = p;            p += 8192;
  u16* wal  = p;            p += 8192;
  u16* lowh = p;            p += 32768;
  u16* lowl = p;            p += 32768;

  k_pre<<<2408, 256, 0, stream>>>(w1, w2, fcw, liw, wa, low, x, ln1g, ln1b,
                                  w1b, w2b, fclh, fcll, wah, wal, lowh, lowl,
                                  xnh, xnl);
  k_fa<<<64, 512, 0, stream>>>(xnh, xnl, fclh, fcll, wah, wal, fcb, lib,
                               y_, u_, ar_, ai_);
  k_scan2<<<128, 64, 0, stream>>>(u_, ar_, ai_, hidr, hidi, h_);
  k_midln<<<64, 512, 0, stream>>>(h_, y_, lowh, lowl, lob, x, ln2g, ln2b,
                                  x2_, xn2b);
  k_ffn1<<<dim3(32, 16), 256, 0, stream>>>(xn2b, w1b, b1, h1b);
  k_ffn2<<<dim3(32, 16), 256, 0, stream>>>(h1b, w2b, b2, x2_, out);
}

// Round 9
// 64.738 us; speedup vs baseline: 1.2406x; 1.2406x over previous
//
#include <hip/hip_runtime.h>
#include <math.h>

#define LSEQ 512
#define DMODEL 512
#define DT 64
#define DFF 2048

typedef unsigned short u16;
typedef __attribute__((ext_vector_type(8))) short short8;
typedef __attribute__((ext_vector_type(4))) float f32x4;

__device__ __forceinline__ float wave_sum(float v) {
#pragma unroll
  for (int o = 32; o > 0; o >>= 1) v += __shfl_xor(v, o, 64);
  return v;
}

__device__ __forceinline__ u16 f2bf(float f) {
  unsigned int u = __float_as_uint(f);
  u += 0x7fffu + ((u >> 16) & 1u);
  return (u16)(u >> 16);
}
__device__ __forceinline__ float bf2f(u16 h) {
  return __uint_as_float(((unsigned int)h) << 16);
}
__device__ __forceinline__ void splitbf(float f, u16& h, u16& l) {
  h = f2bf(f);
  l = f2bf(f - bf2f(h));
}

__device__ __forceinline__ void gload_lds16(const void* g, void* l) {
  __builtin_amdgcn_global_load_lds(
      (const __attribute__((address_space(1))) unsigned int*)g,
      (__attribute__((address_space(3))) unsigned int*)l, 16, 0, 0);
}

// ---------------- k_pre: weight cvt (w1,w2 plain bf16; small weights hi+lo) + LN1 ----
__global__ __launch_bounds__(256) void k_pre(
    const float* __restrict__ w1, const float* __restrict__ w2,
    const float* __restrict__ fcw, const float* __restrict__ liw,
    const float* __restrict__ wa, const float* __restrict__ low,
    const float* __restrict__ x, const float* __restrict__ g1,
    const float* __restrict__ be1,
    u16* __restrict__ w1b, u16* __restrict__ w2b,
    u16* __restrict__ fclh, u16* __restrict__ fcll,
    u16* __restrict__ wah, u16* __restrict__ wal,
    u16* __restrict__ lowh, u16* __restrict__ lowl,
    u16* __restrict__ xnh, u16* __restrict__ xnl)
{
  if (blockIdx.x >= 2152) {                  // ---- LN1: 256 blocks x 4 rows ----
    const int lane = threadIdx.x & 63, wv = threadIdx.x >> 6;
    const int row = (blockIdx.x - 2152) * 4 + wv;
    const float* xr = x + (size_t)row * DMODEL;
    float v[8]; float s = 0.f;
#pragma unroll
    for (int j = 0; j < 8; ++j) { v[j] = xr[lane + 64 * j]; s += v[j]; }
    s = wave_sum(s);
    const float mu = s * (1.f / 512.f);
    float q = 0.f;
#pragma unroll
    for (int j = 0; j < 8; ++j) { float dd = v[j] - mu; q += dd * dd; }
    q = wave_sum(q);
    const float rstd = rsqrtf(q * (1.f / 512.f) + 1e-5f);
#pragma unroll
    for (int j = 0; j < 8; ++j) {
      int idx = lane + 64 * j;
      float o = (v[j] - mu) * rstd * g1[idx] + be1[idx];
      u16 h, l; splitbf(o, h, l);
      xnh[(size_t)row * DMODEL + idx] = h;
      xnl[(size_t)row * DMODEL + idx] = l;
    }
    return;
  }
  int i = blockIdx.x * 256 + threadIdx.x;
  if (i >= 550912) return;
  if (i < 524288) {                          // w1 / w2: plain bf16
    const float* s = (i < 262144) ? w1 : w2;
    u16* d = (i < 262144) ? w1b : w2b;
    int off = (i < 262144) ? i : i - 262144;
    float4 v = ((const float4*)s)[off];
    ushort4 o;
    o.x = f2bf(v.x); o.y = f2bf(v.y); o.z = f2bf(v.z); o.w = f2bf(v.w);
    ((ushort4*)d)[off] = o;
    return;
  }
  const float* s; int j; u16 *dh, *dl;
  if (i < 532480)      { s = fcw; j = i - 524288;        dh = fclh; dl = fcll; }
  else if (i < 540672) { s = liw; j = i - 532480 + 8192; dh = fclh; dl = fcll; }
  else if (i < 542720) { s = wa;  j = i - 540672;        dh = wah;  dl = wal;  }
  else                 { s = low; j = i - 542720;        dh = lowh; dl = lowl; }
  int soff = (i < 532480) ? i - 524288 :
             (i < 540672) ? i - 532480 :
             (i < 542720) ? i - 540672 : i - 542720;
  float4 v = ((const float4*)s)[soff];
  ushort4 oh, ol;
  splitbf(v.x, oh.x, ol.x); splitbf(v.y, oh.y, ol.y);
  splitbf(v.z, oh.z, ol.z); splitbf(v.w, oh.w, ol.w);
  ((ushort4*)dh)[j] = oh;
  ((ushort4*)dl)[j] = ol;
}

// ---------------- k_fa: fused proj(fc+lin_in, bf16x3) + au GEMM + a-map --------------
// 64 blocks x 512 thr (8 waves). Phase1: wave w -> proj col-tile w.
// u (cols 64..127) -> LDS hi/lo; Phase2: wave w -> au col-tile w (N=128).
__global__ __launch_bounds__(512) void k_fa(
    const u16* __restrict__ xnh, const u16* __restrict__ xnl,
    const u16* __restrict__ fclh, const u16* __restrict__ fcll,
    const u16* __restrict__ wah, const u16* __restrict__ wal,
    const float* __restrict__ fcb, const float* __restrict__ lib,
    float* __restrict__ y_o, float* __restrict__ u_o,
    float* __restrict__ ar_o, float* __restrict__ ai_o)
{
  __shared__ __align__(16) u16 ush[16][80];
  __shared__ __align__(16) u16 usl[16][80];
  const int w = threadIdx.x >> 6, lane = threadIdx.x & 63;
  const int mt = blockIdx.x;
  const int lr = lane & 15, lk = lane >> 4;

  {  // phase 1: proj tile, K=512, bf16x3
    const size_t aoff = (size_t)(mt * 16 + lr) * DMODEL + lk * 8;
    const size_t boff = (size_t)(w * 16 + lr) * DMODEL + lk * 8;
    f32x4 acc = {};
#pragma unroll 4
    for (int k = 0; k < DMODEL; k += 32) {
      short8 ah = *(const short8*)(xnh + aoff + k);
      short8 al = *(const short8*)(xnl + aoff + k);
      short8 bh = *(const short8*)(fclh + boff + k);
      short8 bl = *(const short8*)(fcll + boff + k);
      acc = __builtin_amdgcn_mfma_f32_16x16x32_bf16(ah, bh, acc, 0, 0, 0);
      acc = __builtin_amdgcn_mfma_f32_16x16x32_bf16(ah, bl, acc, 0, 0, 0);
      acc = __builtin_amdgcn_mfma_f32_16x16x32_bf16(al, bh, acc, 0, 0, 0);
    }
    const int c = w * 16 + lr;
#pragma unroll
    for (int j = 0; j < 4; ++j) {
      int rl = lk * 4 + j;
      int row = mt * 16 + rl;
      float v = acc[j];
      if (c < DT) {
        v += fcb[c];
        y_o[row * DT + c] = v / (1.f + expf(-v));        // silu gate (fp32)
      } else {
        int d = c - DT;
        v += lib[d];
        u_o[row * DT + d] = v;                           // fp32 for scan
        u16 h, l; splitbf(v, h, l);
        ush[rl][d] = h; usl[rl][d] = l;
      }
    }
  }
  __syncthreads();
  {  // phase 2: au tile nt=w over K=64, bf16x3; then a-map
    const size_t boff = (size_t)(w * 16 + lr) * DT + lk * 8;
    f32x4 acc = {};
#pragma unroll
    for (int ks = 0; ks < 2; ++ks) {
      short8 ah = *(const short8*)&ush[lr][ks * 32 + lk * 8];
      short8 al = *(const short8*)&usl[lr][ks * 32 + lk * 8];
      short8 bh = *(const short8*)(wah + boff + ks * 32);
      short8 bl = *(const short8*)(wal + boff + ks * 32);
      acc = __builtin_amdgcn_mfma_f32_16x16x32_bf16(ah, bh, acc, 0, 0, 0);
      acc = __builtin_amdgcn_mfma_f32_16x16x32_bf16(ah, bl, acc, 0, 0, 0);
      acc = __builtin_amdgcn_mfma_f32_16x16x32_bf16(al, bh, acc, 0, 0, 0);
    }
    const int c = w * 16 + lr;
#pragma unroll
    for (int j = 0; j < 4; ++j) {
      float v = acc[j];
      float p = __shfl_xor(v, 1, 64);
      float re = (lane & 1) ? p : v;
      float im = (lane & 1) ? v : p;
      float asq = re * re + im * im;
      float sc = rsqrtf(asq) * expf(-asq);
      int row = mt * 16 + lk * 4 + j;
      int d = c >> 1;
      if (lane & 1) ai_o[row * DT + d] = im * sc;
      else          ar_o[row * DT + d] = re * sc;
    }
  }
}

// ---------------- parallel backward affine scan (unchanged) --------------------------
__global__ __launch_bounds__(64) void k_scan2(
    const float* __restrict__ u, const float* __restrict__ ar, const float* __restrict__ ai,
    const float* __restrict__ hr, const float* __restrict__ hi, float* __restrict__ h_o)
{
  const int blk = blockIdx.x;             // 0..127
  const int b = blk >> 6, d = blk & 63;
  const int lane = threadIdx.x;           // 0..63
  const size_t base = (size_t)b * LSEQ * DT + d;
  const int i0 = lane * 8;

  float a_r[8], a_i[8], b_r[8], b_i[8];
#pragma unroll
  for (int e = 0; e < 8; ++e) {
    int i = i0 + e;
    a_r[e] = ar[base + (size_t)i * DT];
    a_i[e] = ai[base + (size_t)i * DT];
    if (i >= 2)      { b_r[e] = u[base + (size_t)(i - 2) * DT]; b_i[e] = 0.f; }
    else if (i == 1) { b_r[e] = hr[d]; b_i[e] = hi[d]; }
    else             { b_r[e] = 0.f;   b_i[e] = 0.f; }
  }

  float Ar = 1.f, Ai = 0.f, Br = 0.f, Bi = 0.f;
#pragma unroll
  for (int e = 0; e < 8; ++e) {
    float nBr = fmaf(Ar, b_r[e], fmaf(-Ai, b_i[e], Br));
    float nBi = fmaf(Ar, b_i[e], fmaf( Ai, b_r[e], Bi));
    float nAr = Ar * a_r[e] - Ai * a_i[e];
    float nAi = Ar * a_i[e] + Ai * a_r[e];
    Ar = nAr; Ai = nAi; Br = nBr; Bi = nBi;
  }

#pragma unroll
  for (int dlt = 1; dlt < 64; dlt <<= 1) {
    float Ar2 = __shfl_down(Ar, dlt, 64);
    float Ai2 = __shfl_down(Ai, dlt, 64);
    float Br2 = __shfl_down(Br, dlt, 64);
    float Bi2 = __shfl_down(Bi, dlt, 64);
    if (lane + dlt < 64) {
      float nAr = Ar * Ar2 - Ai * Ai2;
      float nAi = Ar * Ai2 + Ai * Ar2;
      float nBr = fmaf(Ar, Br2, fmaf(-Ai, Bi2, Br));
      float nBi = fmaf(Ar, Bi2, fmaf( Ai, Br2, Bi));
      Ar = nAr; Ai = nAi; Br = nBr; Bi = nBi;
    }
  }

  float A1r = __shfl_down(Ar, 1, 64), A1i = __shfl_down(Ai, 1, 64);
  float B1r = __shfl_down(Br, 1, 64), B1i = __shfl_down(Bi, 1, 64);
  if (lane == 63) { A1r = 1.f; A1i = 0.f; B1r = 0.f; B1i = 0.f; }
  const float r512 = u[base + (size_t)(LSEQ - 2) * DT];
  float rr = fmaf(A1r, r512, B1r);
  float ri = fmaf(A1i, r512, B1i);

  const float uL = u[base + (size_t)(LSEQ - 1) * DT];
#pragma unroll
  for (int e = 7; e >= 0; --e) {
    int i = i0 + e;
    float nr = fmaf(a_r[e], rr, fmaf(-a_i[e], ri, b_r[e]));
    float ni = fmaf(a_r[e], ri, fmaf( a_i[e], rr, b_i[e]));
    rr = nr; ri = ni;
    float outv = rr;
    if (i == LSEQ - 1) outv += uL;
    h_o[base + (size_t)i * DT] = outv;
  }
}

// ---------------- k_midln: x2 = (h*y)@low^T+lob+x (bf16x3) then LN2 -> bf16 ----------
// 64 blocks x 1024 thr (16 waves): phase0 hy->LDS; phase1 2 col-tiles/wave;
// phase2 LN2 1 row/wave.
__global__ __launch_bounds__(1024) void k_midln(
    const float* __restrict__ h, const float* __restrict__ y,
    const u16* __restrict__ lowh, const u16* __restrict__ lowl,
    const float* __restrict__ lob, const float* __restrict__ x,
    const float* __restrict__ g2, const float* __restrict__ be2,
    float* __restrict__ x2_o, u16* __restrict__ xn2b)
{
  __shared__ __align__(16) u16 hyh[16][80];
  __shared__ __align__(16) u16 hyl[16][80];
  __shared__ float x2s[16][520];
  const int tid = threadIdx.x;
  const int w = tid >> 6, lane = tid & 63;
  const int lr = lane & 15, lk = lane >> 4;
  const int mt = blockIdx.x;

  {                                            // phase 0: hy hi/lo (1024 = 16x64)
    int r = tid >> 6, d = tid & 63;
    int row = mt * 16 + r;
    float v = h[row * DT + d] * y[row * DT + d];
    u16 hh, ll; splitbf(v, hh, ll);
    hyh[r][d] = hh; hyl[r][d] = ll;
  }
  __syncthreads();

#pragma unroll
  for (int t = 0; t < 2; ++t) {                // phase 1: tiles nt = w*2+t
    const int nt = w * 2 + t;
    const size_t boff = (size_t)(nt * 16 + lr) * DT + lk * 8;
    f32x4 acc = {};
#pragma unroll
    for (int ks = 0; ks < 2; ++ks) {
      short8 ah = *(const short8*)&hyh[lr][ks * 32 + lk * 8];
      short8 al = *(const short8*)&hyl[lr][ks * 32 + lk * 8];
      short8 bh = *(const short8*)(lowh + boff + ks * 32);
      short8 bl = *(const short8*)(lowl + boff + ks * 32);
      acc = __builtin_amdgcn_mfma_f32_16x16x32_bf16(ah, bh, acc, 0, 0, 0);
      acc = __builtin_amdgcn_mfma_f32_16x16x32_bf16(ah, bl, acc, 0, 0, 0);
      acc = __builtin_amdgcn_mfma_f32_16x16x32_bf16(al, bh, acc, 0, 0, 0);
    }
    const int c = nt * 16 + lr;
#pragma unroll
    for (int j = 0; j < 4; ++j) {
      int rl = lk * 4 + j;
      int row = mt * 16 + rl;
      float v = acc[j] + lob[c] + x[(size_t)row * DMODEL + c];
      x2s[rl][c] = v;
      x2_o[(size_t)row * DMODEL + c] = v;
    }
  }
  __syncthreads();

  {                                            // phase 2: LN2, row w per wave
    const int r = w;
    const int row = mt * 16 + r;
    float v[8]; float s = 0.f;
#pragma unroll
    for (int j = 0; j < 8; ++j) { v[j] = x2s[r][lane + 64 * j]; s += v[j]; }
    s = wave_sum(s);
    const float mu = s * (1.f / 512.f);
    float q = 0.f;
#pragma unroll
    for (int j = 0; j < 8; ++j) { float dd = v[j] - mu; q += dd * dd; }
    q = wave_sum(q);
    const float rstd = rsqrtf(q * (1.f / 512.f) + 1e-5f);
#pragma unroll
    for (int j = 0; j < 8; ++j) {
      int idx = lane + 64 * j;
      xn2b[(size_t)row * DMODEL + idx] = f2bf((v[j] - mu) * rstd * g2[idx] + be2[idx]);
    }
  }
}

// ---------------- bf16 MFMA GEMM (FFN), LDS-staged (round-7 proven) ------------------
// EPI=0: silu(acc+bias) -> bf16 Cb.   EPI=2: raw acc -> Cf + blockIdx.z*partStride.
template<int BM, int BN, int EPI>
__global__ __launch_bounds__(256) void k_mfma(
    const u16* __restrict__ A, const u16* __restrict__ B,
    const float* __restrict__ bias, float* __restrict__ Cf, u16* __restrict__ Cb,
    int K, int N, int kTiles, int partStride)
{
  constexpr int MF = BM / 32, NF = BN / 32;
  __shared__ __align__(16) u16 As[BM * 64];
  __shared__ __align__(16) u16 Bs[BN * 64];
  const int t = threadIdx.x;
  const int m0 = blockIdx.x * BM, n0 = blockIdx.y * BN;
  const int kBase = blockIdx.z * kTiles * 64;
  const int w = t >> 6, lane = t & 63;
  const int wm = w >> 1, wn = w & 1;
  const int lr = lane & 15, lk = lane >> 4;
  f32x4 acc[MF][NF] = {};

  for (int kt = 0; kt < kTiles; ++kt) {
    const int k0 = kBase + kt * 64;
#pragma unroll
    for (int i = 0; i < BM / 32; ++i) {
      int e = i * 2048 + t * 8;
      int row = e >> 6, col = e & 63;
      gload_lds16(A + (size_t)(m0 + row) * K + k0 + col, &As[e]);
    }
#pragma unroll
    for (int i = 0; i < BN / 32; ++i) {
      int e = i * 2048 + t * 8;
      int row = e >> 6, col = e & 63;
      gload_lds16(B + (size_t)(n0 + row) * K + k0 + col, &Bs[e]);
    }
    __syncthreads();
#pragma unroll
    for (int ks = 0; ks < 2; ++ks) {
      short8 af[MF], bf[NF];
#pragma unroll
      for (int mf = 0; mf < MF; ++mf)
        af[mf] = *(const short8*)&As[(wm * (BM / 2) + mf * 16 + lr) * 64 + ks * 32 + lk * 8];
#pragma unroll
      for (int nf = 0; nf < NF; ++nf)
        bf[nf] = *(const short8*)&Bs[(wn * (BN / 2) + nf * 16 + lr) * 64 + ks * 32 + lk * 8];
#pragma unroll
      for (int mf = 0; mf < MF; ++mf)
#pragma unroll
        for (int nf = 0; nf < NF; ++nf)
          acc[mf][nf] = __builtin_amdgcn_mfma_f32_16x16x32_bf16(af[mf], bf[nf], acc[mf][nf], 0, 0, 0);
    }
    __syncthreads();
  }

#pragma unroll
  for (int mf = 0; mf < MF; ++mf)
#pragma unroll
    for (int nf = 0; nf < NF; ++nf)
#pragma unroll
      for (int j = 0; j < 4; ++j) {
        int rrow = m0 + wm * (BM / 2) + mf * 16 + lk * 4 + j;
        int ccol = n0 + wn * (BN / 2) + nf * 16 + lr;
        if constexpr (EPI == 0) {
          float v = acc[mf][nf][j] + bias[ccol];
          v = v / (1.f + expf(-v));                       // silu
          Cb[(size_t)rrow * N + ccol] = f2bf(v);
        } else {
          Cf[(size_t)blockIdx.z * partStride + (size_t)rrow * N + ccol] = acc[mf][nf][j];
        }
      }
}

// ---------------- split-K reduce: out = p0+p1+p2+p3 + b2 + x2 (stride in float4!) ----
__global__ __launch_bounds__(256) void k_red(
    const float* __restrict__ p, const float* __restrict__ b2,
    const float* __restrict__ x2, float* __restrict__ out, int n4, int partStride4)
{
  int i = blockIdx.x * 256 + threadIdx.x;
  if (i >= n4) return;
  const float4* p4 = (const float4*)p;
  float4 s = p4[i];
  float4 s1 = p4[i + partStride4];
  float4 s2 = p4[i + 2 * partStride4];
  float4 s3 = p4[i + 3 * partStride4];
  s.x += s1.x; s.y += s1.y; s.z += s1.z; s.w += s1.w;
  s.x += s2.x; s.y += s2.y; s.z += s2.z; s.w += s2.w;
  s.x += s3.x; s.y += s3.y; s.z += s3.z; s.w += s3.w;
  int col4 = i & 127;                       // N=512 -> 128 float4 per row
  float4 bb = ((const float4*)b2)[col4];
  float4 rr = ((const float4*)x2)[i];
  s.x += bb.x + rr.x; s.y += bb.y + rr.y; s.z += bb.z + rr.z; s.w += bb.w + rr.w;
  ((float4*)out)[i] = s;
}

// ---------------- launch -------------------------------------------------------------
extern "C" void kernel_launch(void* const* d_in, const int* in_sizes, int n_in,
                              void* d_out, int out_size, void* d_ws, size_t ws_size,
                              hipStream_t stream) {
  const float* x    = (const float*)d_in[0];
  const float* ln1g = (const float*)d_in[1];
  const float* ln1b = (const float*)d_in[2];
  const float* fcw  = (const float*)d_in[3];
  const float* fcb  = (const float*)d_in[4];
  const float* liw  = (const float*)d_in[5];
  const float* lib  = (const float*)d_in[6];
  const float* wa   = (const float*)d_in[7];
  const float* hidr = (const float*)d_in[8];
  const float* hidi = (const float*)d_in[9];
  const float* low  = (const float*)d_in[10];
  const float* lob  = (const float*)d_in[11];
  const float* ln2g = (const float*)d_in[12];
  const float* ln2b = (const float*)d_in[13];
  const float* w1   = (const float*)d_in[14];
  const float* b1   = (const float*)d_in[15];
  const float* w2   = (const float*)d_in[16];
  const float* b2   = (const float*)d_in[17];
  float* out = (float*)d_out;
  float* ws  = (float*)d_ws;

  const int R = 2 * LSEQ;                      // 1024 rows
  float* y_    = ws;                           // 65536
  float* u_    = y_   + 65536;
  float* ar_   = u_   + 65536;
  float* ai_   = ar_  + 65536;
  float* h_    = ai_  + 65536;
  float* x2_   = h_   + 65536;                 // 524288
  float* part_ = x2_  + 524288;                // 2097152
  u16* p = (u16*)(part_ + 2097152);
  u16* xnh  = p;            p += 524288;
  u16* xnl  = p;            p += 524288;
  u16* xn2b = p;            p += 524288;
  u16* h1b  = p;            p += 2097152;
  u16* w1b  = p;            p += 1048576;
  u16* w2b  = p;            p += 1048576;
  u16* fclh = p;            p += 65536;
  u16* fcll = p;            p += 65536;
  u16* wah  = p;            p += 8192;
  u16* wal  = p;            p += 8192;
  u16* lowh = p;            p += 32768;
  u16* lowl = p;            p += 32768;

  k_pre<<<2408, 256, 0, stream>>>(w1, w2, fcw, liw, wa, low, x, ln1g, ln1b,
                                  w1b, w2b, fclh, fcll, wah, wal, lowh, lowl,
                                  xnh, xnl);
  k_fa<<<64, 512, 0, stream>>>(xnh, xnl, fclh, fcll, wah, wal, fcb, lib,
                               y_, u_, ar_, ai_);
  k_scan2<<<128, 64, 0, stream>>>(u_, ar_, ai_, hidr, hidi, h_);
  k_midln<<<64, 1024, 0, stream>>>(h_, y_, lowh, lowl, lob, x, ln2g, ln2b,
                                   x2_, xn2b);
  dim3 g1(R / 64, DFF / 64);                   // (16,32) = 512 blocks
  k_mfma<64, 64, 0><<<g1, 256, 0, stream>>>(xn2b, w1b, b1, nullptr, h1b,
                                            DMODEL, DFF, DMODEL / 64, 0);
  dim3 g2(R / 64, DMODEL / 64, 4);             // 512 blocks, split-K x4
  k_mfma<64, 64, 2><<<g2, 256, 0, stream>>>(h1b, w2b, nullptr, part_, nullptr,
                                            DFF, DMODEL, (DFF / 4) / 64, R * DMODEL);
  k_red<<<(R * DMODEL / 4 + 255) / 256, 256, 0, stream>>>(part_, b2, x2_, out,
                                                          R * DMODEL / 4, R * DMODEL / 4);
}

// Round 10
// 62.860 us; speedup vs baseline: 1.2777x; 1.0299x over previous
//
#include <hip/hip_runtime.h>
#include <math.h>

#define LSEQ 512
#define DMODEL 512
#define DT 64
#define DFF 2048

typedef unsigned short u16;
typedef __attribute__((ext_vector_type(8))) short short8;
typedef __attribute__((ext_vector_type(4))) float f32x4;
typedef __attribute__((ext_vector_type(16))) float f32x16;

__device__ __forceinline__ float wave_sum(float v) {
#pragma unroll
  for (int o = 32; o > 0; o >>= 1) v += __shfl_xor(v, o, 64);
  return v;
}

__device__ __forceinline__ u16 f2bf(float f) {
  unsigned int u = __float_as_uint(f);
  u += 0x7fffu + ((u >> 16) & 1u);
  return (u16)(u >> 16);
}
__device__ __forceinline__ float bf2f(u16 h) {
  return __uint_as_float(((unsigned int)h) << 16);
}
__device__ __forceinline__ void splitbf(float f, u16& h, u16& l) {
  h = f2bf(f);
  l = f2bf(f - bf2f(h));
}

// Swizzled fragment-ready layout for 32x32x16 MFMA operands, matrix X[R][C]:
//   t = r/32, r32 = r%32, kb = c/16, half = (c%16)/8, e = c%8, lane = r32 + 32*half
//   flat(u16) = t*(C*32) + kb*512 + lane*8 + e
// Wave fragment load for tile t, k-block kb:  &X'[t*(C*32) + kb*512 + lane*8]  (coalesced)

// ---------------- k_pre: w1,w2 -> SWIZZLED bf16; small weights hi/lo; LN1 ------------
__global__ __launch_bounds__(256) void k_pre(
    const float* __restrict__ w1, const float* __restrict__ w2,
    const float* __restrict__ fcw, const float* __restrict__ liw,
    const float* __restrict__ wa, const float* __restrict__ low,
    const float* __restrict__ x, const float* __restrict__ g1,
    const float* __restrict__ be1,
    u16* __restrict__ w1s, u16* __restrict__ w2s,
    u16* __restrict__ fclh, u16* __restrict__ fcll,
    u16* __restrict__ wah, u16* __restrict__ wal,
    u16* __restrict__ lowh, u16* __restrict__ lowl,
    u16* __restrict__ xnh, u16* __restrict__ xnl)
{
  if (blockIdx.x >= 2152) {                  // ---- LN1: 256 blocks x 4 rows ----
    const int lane = threadIdx.x & 63, wv = threadIdx.x >> 6;
    const int row = (blockIdx.x - 2152) * 4 + wv;
    const float* xr = x + (size_t)row * DMODEL;
    float v[8]; float s = 0.f;
#pragma unroll
    for (int j = 0; j < 8; ++j) { v[j] = xr[lane + 64 * j]; s += v[j]; }
    s = wave_sum(s);
    const float mu = s * (1.f / 512.f);
    float q = 0.f;
#pragma unroll
    for (int j = 0; j < 8; ++j) { float dd = v[j] - mu; q += dd * dd; }
    q = wave_sum(q);
    const float rstd = rsqrtf(q * (1.f / 512.f) + 1e-5f);
#pragma unroll
    for (int j = 0; j < 8; ++j) {
      int idx = lane + 64 * j;
      float o = (v[j] - mu) * rstd * g1[idx] + be1[idx];
      u16 h, l; splitbf(o, h, l);
      xnh[(size_t)row * DMODEL + idx] = h;
      xnl[(size_t)row * DMODEL + idx] = l;
    }
    return;
  }
  int i = blockIdx.x * 256 + threadIdx.x;
  if (i >= 550912) return;
  if (i < 262144) {                          // w1 (2048x512) -> swizzled bf16
    int r = i >> 7, c0 = (i & 127) << 2;     // 128 float4 per row
    float4 v = ((const float4*)w1)[i];
    ushort4 o;
    o.x = f2bf(v.x); o.y = f2bf(v.y); o.z = f2bf(v.z); o.w = f2bf(v.w);
    int lane = (r & 31) + (((c0 & 15) >> 3) << 5);
    int flat = (r >> 5) * 16384 + (c0 >> 4) * 512 + lane * 8 + (c0 & 7);
    *(ushort4*)(w1s + flat) = o;
    return;
  }
  if (i < 524288) {                          // w2 (512x2048) -> swizzled bf16
    int ii = i - 262144;
    int r = ii >> 9, c0 = (ii & 511) << 2;   // 512 float4 per row
    float4 v = ((const float4*)w2)[ii];
    ushort4 o;
    o.x = f2bf(v.x); o.y = f2bf(v.y); o.z = f2bf(v.z); o.w = f2bf(v.w);
    int lane = (r & 31) + (((c0 & 15) >> 3) << 5);
    int flat = (r >> 5) * 65536 + (c0 >> 4) * 512 + lane * 8 + (c0 & 7);
    *(ushort4*)(w2s + flat) = o;
    return;
  }
  const float* s; int j; u16 *dh, *dl;
  if (i < 532480)      { s = fcw; j = i - 524288;        dh = fclh; dl = fcll; }
  else if (i < 540672) { s = liw; j = i - 532480 + 8192; dh = fclh; dl = fcll; }
  else if (i < 542720) { s = wa;  j = i - 540672;        dh = wah;  dl = wal;  }
  else                 { s = low; j = i - 542720;        dh = lowh; dl = lowl; }
  int soff = (i < 532480) ? i - 524288 :
             (i < 540672) ? i - 532480 :
             (i < 542720) ? i - 540672 : i - 542720;
  float4 v = ((const float4*)s)[soff];
  ushort4 oh, ol;
  splitbf(v.x, oh.x, ol.x); splitbf(v.y, oh.y, ol.y);
  splitbf(v.z, oh.z, ol.z); splitbf(v.w, oh.w, ol.w);
  ((ushort4*)dh)[j] = oh;
  ((ushort4*)dl)[j] = ol;
}

// ---------------- k_fa: fused proj(fc+lin_in, bf16x3) + au GEMM + a-map --------------
__global__ __launch_bounds__(512) void k_fa(
    const u16* __restrict__ xnh, const u16* __restrict__ xnl,
    const u16* __restrict__ fclh, const u16* __restrict__ fcll,
    const u16* __restrict__ wah, const u16* __restrict__ wal,
    const float* __restrict__ fcb, const float* __restrict__ lib,
    float* __restrict__ y_o, float* __restrict__ u_o,
    float* __restrict__ ar_o, float* __restrict__ ai_o)
{
  __shared__ __align__(16) u16 ush[16][80];
  __shared__ __align__(16) u16 usl[16][80];
  const int w = threadIdx.x >> 6, lane = threadIdx.x & 63;
  const int mt = blockIdx.x;
  const int lr = lane & 15, lk = lane >> 4;

  {  // phase 1: proj tile, K=512, bf16x3
    const size_t aoff = (size_t)(mt * 16 + lr) * DMODEL + lk * 8;
    const size_t boff = (size_t)(w * 16 + lr) * DMODEL + lk * 8;
    f32x4 acc = {};
#pragma unroll 4
    for (int k = 0; k < DMODEL; k += 32) {
      short8 ah = *(const short8*)(xnh + aoff + k);
      short8 al = *(const short8*)(xnl + aoff + k);
      short8 bh = *(const short8*)(fclh + boff + k);
      short8 bl = *(const short8*)(fcll + boff + k);
      acc = __builtin_amdgcn_mfma_f32_16x16x32_bf16(ah, bh, acc, 0, 0, 0);
      acc = __builtin_amdgcn_mfma_f32_16x16x32_bf16(ah, bl, acc, 0, 0, 0);
      acc = __builtin_amdgcn_mfma_f32_16x16x32_bf16(al, bh, acc, 0, 0, 0);
    }
    const int c = w * 16 + lr;
#pragma unroll
    for (int j = 0; j < 4; ++j) {
      int rl = lk * 4 + j;
      int row = mt * 16 + rl;
      float v = acc[j];
      if (c < DT) {
        v += fcb[c];
        y_o[row * DT + c] = v / (1.f + expf(-v));        // silu gate (fp32)
      } else {
        int d = c - DT;
        v += lib[d];
        u_o[row * DT + d] = v;                           // fp32 for scan
        u16 h, l; splitbf(v, h, l);
        ush[rl][d] = h; usl[rl][d] = l;
      }
    }
  }
  __syncthreads();
  {  // phase 2: au tile nt=w over K=64, bf16x3; then a-map
    const size_t boff = (size_t)(w * 16 + lr) * DT + lk * 8;
    f32x4 acc = {};
#pragma unroll
    for (int ks = 0; ks < 2; ++ks) {
      short8 ah = *(const short8*)&ush[lr][ks * 32 + lk * 8];
      short8 al = *(const short8*)&usl[lr][ks * 32 + lk * 8];
      short8 bh = *(const short8*)(wah + boff + ks * 32);
      short8 bl = *(const short8*)(wal + boff + ks * 32);
      acc = __builtin_amdgcn_mfma_f32_16x16x32_bf16(ah, bh, acc, 0, 0, 0);
      acc = __builtin_amdgcn_mfma_f32_16x16x32_bf16(ah, bl, acc, 0, 0, 0);
      acc = __builtin_amdgcn_mfma_f32_16x16x32_bf16(al, bh, acc, 0, 0, 0);
    }
    const int c = w * 16 + lr;
#pragma unroll
    for (int j = 0; j < 4; ++j) {
      float v = acc[j];
      float p = __shfl_xor(v, 1, 64);
      float re = (lane & 1) ? p : v;
      float im = (lane & 1) ? v : p;
      float asq = re * re + im * im;
      float sc = rsqrtf(asq) * expf(-asq);
      int row = mt * 16 + lk * 4 + j;
      int d = c >> 1;
      if (lane & 1) ai_o[row * DT + d] = im * sc;
      else          ar_o[row * DT + d] = re * sc;
    }
  }
}

// ---------------- parallel backward affine scan (unchanged) --------------------------
__global__ __launch_bounds__(64) void k_scan2(
    const float* __restrict__ u, const float* __restrict__ ar, const float* __restrict__ ai,
    const float* __restrict__ hr, const float* __restrict__ hi, float* __restrict__ h_o)
{
  const int blk = blockIdx.x;             // 0..127
  const int b = blk >> 6, d = blk & 63;
  const int lane = threadIdx.x;           // 0..63
  const size_t base = (size_t)b * LSEQ * DT + d;
  const int i0 = lane * 8;

  float a_r[8], a_i[8], b_r[8], b_i[8];
#pragma unroll
  for (int e = 0; e < 8; ++e) {
    int i = i0 + e;
    a_r[e] = ar[base + (size_t)i * DT];
    a_i[e] = ai[base + (size_t)i * DT];
    if (i >= 2)      { b_r[e] = u[base + (size_t)(i - 2) * DT]; b_i[e] = 0.f; }
    else if (i == 1) { b_r[e] = hr[d]; b_i[e] = hi[d]; }
    else             { b_r[e] = 0.f;   b_i[e] = 0.f; }
  }

  float Ar = 1.f, Ai = 0.f, Br = 0.f, Bi = 0.f;
#pragma unroll
  for (int e = 0; e < 8; ++e) {
    float nBr = fmaf(Ar, b_r[e], fmaf(-Ai, b_i[e], Br));
    float nBi = fmaf(Ar, b_i[e], fmaf( Ai, b_r[e], Bi));
    float nAr = Ar * a_r[e] - Ai * a_i[e];
    float nAi = Ar * a_i[e] + Ai * a_r[e];
    Ar = nAr; Ai = nAi; Br = nBr; Bi = nBi;
  }

#pragma unroll
  for (int dlt = 1; dlt < 64; dlt <<= 1) {
    float Ar2 = __shfl_down(Ar, dlt, 64);
    float Ai2 = __shfl_down(Ai, dlt, 64);
    float Br2 = __shfl_down(Br, dlt, 64);
    float Bi2 = __shfl_down(Bi, dlt, 64);
    if (lane + dlt < 64) {
      float nAr = Ar * Ar2 - Ai * Ai2;
      float nAi = Ar * Ai2 + Ai * Ar2;
      float nBr = fmaf(Ar, Br2, fmaf(-Ai, Bi2, Br));
      float nBi = fmaf(Ar, Bi2, fmaf( Ai, Br2, Bi));
      Ar = nAr; Ai = nAi; Br = nBr; Bi = nBi;
    }
  }

  float A1r = __shfl_down(Ar, 1, 64), A1i = __shfl_down(Ai, 1, 64);
  float B1r = __shfl_down(Br, 1, 64), B1i = __shfl_down(Bi, 1, 64);
  if (lane == 63) { A1r = 1.f; A1i = 0.f; B1r = 0.f; B1i = 0.f; }
  const float r512 = u[base + (size_t)(LSEQ - 2) * DT];
  float rr = fmaf(A1r, r512, B1r);
  float ri = fmaf(A1i, r512, B1i);

  const float uL = u[base + (size_t)(LSEQ - 1) * DT];
#pragma unroll
  for (int e = 7; e >= 0; --e) {
    int i = i0 + e;
    float nr = fmaf(a_r[e], rr, fmaf(-a_i[e], ri, b_r[e]));
    float ni = fmaf(a_r[e], ri, fmaf( a_i[e], rr, b_i[e]));
    rr = nr; ri = ni;
    float outv = rr;
    if (i == LSEQ - 1) outv += uL;
    h_o[base + (size_t)i * DT] = outv;
  }
}

// ---------------- k_midln: x2 = (h*y)@low^T+lob+x (bf16x3), LN2 -> SWIZZLED xn2 ------
__global__ __launch_bounds__(1024) void k_midln(
    const float* __restrict__ h, const float* __restrict__ y,
    const u16* __restrict__ lowh, const u16* __restrict__ lowl,
    const float* __restrict__ lob, const float* __restrict__ x,
    const float* __restrict__ g2, const float* __restrict__ be2,
    float* __restrict__ x2_o, u16* __restrict__ xn2s)
{
  __shared__ __align__(16) u16 hyh[16][80];
  __shared__ __align__(16) u16 hyl[16][80];
  __shared__ float x2s[16][520];
  const int tid = threadIdx.x;
  const int w = tid >> 6, lane = tid & 63;
  const int lr = lane & 15, lk = lane >> 4;
  const int mt = blockIdx.x;

  {                                            // phase 0: hy hi/lo
    int r = tid >> 6, d = tid & 63;
    int row = mt * 16 + r;
    float v = h[row * DT + d] * y[row * DT + d];
    u16 hh, ll; splitbf(v, hh, ll);
    hyh[r][d] = hh; hyl[r][d] = ll;
  }
  __syncthreads();

#pragma unroll
  for (int t = 0; t < 2; ++t) {                // phase 1: tiles nt = w*2+t
    const int nt = w * 2 + t;
    const size_t boff = (size_t)(nt * 16 + lr) * DT + lk * 8;
    f32x4 acc = {};
#pragma unroll
    for (int ks = 0; ks < 2; ++ks) {
      short8 ah = *(const short8*)&hyh[lr][ks * 32 + lk * 8];
      short8 al = *(const short8*)&hyl[lr][ks * 32 + lk * 8];
      short8 bh = *(const short8*)(lowh + boff + ks * 32);
      short8 bl = *(const short8*)(lowl + boff + ks * 32);
      acc = __builtin_amdgcn_mfma_f32_16x16x32_bf16(ah, bh, acc, 0, 0, 0);
      acc = __builtin_amdgcn_mfma_f32_16x16x32_bf16(ah, bl, acc, 0, 0, 0);
      acc = __builtin_amdgcn_mfma_f32_16x16x32_bf16(al, bh, acc, 0, 0, 0);
    }
    const int c = nt * 16 + lr;
#pragma unroll
    for (int j = 0; j < 4; ++j) {
      int rl = lk * 4 + j;
      int row = mt * 16 + rl;
      float v = acc[j] + lob[c] + x[(size_t)row * DMODEL + c];
      x2s[rl][c] = v;
      x2_o[(size_t)row * DMODEL + c] = v;
    }
  }
  __syncthreads();

  {                                            // phase 2: LN2, row w; swizzled store
    const int r = w;
    const int row = mt * 16 + r;
    float v[8]; float s = 0.f;
#pragma unroll
    for (int j = 0; j < 8; ++j) { v[j] = x2s[r][lane + 64 * j]; s += v[j]; }
    s = wave_sum(s);
    const float mu = s * (1.f / 512.f);
    float q = 0.f;
#pragma unroll
    for (int j = 0; j < 8; ++j) { float dd = v[j] - mu; q += dd * dd; }
    q = wave_sum(q);
    const float rstd = rsqrtf(q * (1.f / 512.f) + 1e-5f);
    const int t32 = row >> 5, r32 = row & 31;
#pragma unroll
    for (int j = 0; j < 8; ++j) {
      int idx = lane + 64 * j;
      float o = (v[j] - mu) * rstd * g2[idx] + be2[idx];
      int lane_s = r32 + (((idx & 15) >> 3) << 5);
      xn2s[t32 * 16384 + (idx >> 4) * 512 + lane_s * 8 + (idx & 7)] = f2bf(o);
    }
  }
}

// ---------------- k_ffn1: h1 = silu(xn2 @ w1^T + b1); barrier-free, swizzled I/O -----
// grid (32,16) x 256 thr; wave w -> nt = by*4+w (64 nt). All frag loads coalesced.
__global__ __launch_bounds__(256) void k_ffn1(
    const u16* __restrict__ As, const u16* __restrict__ Bs,
    const float* __restrict__ bias, u16* __restrict__ Cs)
{
  const int w = threadIdx.x >> 6, lane = threadIdx.x & 63;
  const int mt = blockIdx.x, nt = blockIdx.y * 4 + w;
  const u16* a = As + mt * 16384 + lane * 8;
  const u16* b = Bs + nt * 16384 + lane * 8;
  f32x16 acc = {};
#pragma unroll 8
  for (int kb = 0; kb < 32; ++kb)
    acc = __builtin_amdgcn_mfma_f32_32x32x16_bf16(*(const short8*)(a + kb * 512),
                                                  *(const short8*)(b + kb * 512),
                                                  acc, 0, 0, 0);
  const int l31 = lane & 31, hi = lane >> 5;
  const int col = nt * 32 + l31;
  const float bb = bias[col];
  const int kb_c = col >> 4;                     // swizzled h1 coords from col
  const int half_c = (col & 15) >> 3, e_c = col & 7;
#pragma unroll
  for (int r = 0; r < 16; ++r) {
    int row32 = (r & 3) + 8 * (r >> 2) + 4 * hi;
    float v = acc[r] + bb;
    v = v / (1.f + expf(-v));                    // silu
    int lane_s = row32 + (half_c << 5);
    Cs[mt * 65536 + kb_c * 512 + lane_s * 8 + e_c] = f2bf(v);
  }
}

// ---------------- k_ffn2: out = h1 @ w2^T + b2 + x2; 4-wave in-block split-K ---------
// grid (32,16) x 256 thr; wave w = K-quarter; swizzled coalesced frag loads;
// LDS reduce (order w=0..3 == old k_red order); fused epilogue.
__global__ __launch_bounds__(256) void k_ffn2(
    const u16* __restrict__ As, const u16* __restrict__ Bs,
    const float* __restrict__ b2, const float* __restrict__ x2,
    float* __restrict__ out)
{
  __shared__ float red[4][16][64];
  const int w = threadIdx.x >> 6, lane = threadIdx.x & 63;
  const int mt = blockIdx.x, nt = blockIdx.y;
  const u16* a = As + mt * 65536 + w * 32 * 512 + lane * 8;
  const u16* b = Bs + nt * 65536 + w * 32 * 512 + lane * 8;
  f32x16 acc = {};
#pragma unroll 8
  for (int kb = 0; kb < 32; ++kb)
    acc = __builtin_amdgcn_mfma_f32_32x32x16_bf16(*(const short8*)(a + kb * 512),
                                                  *(const short8*)(b + kb * 512),
                                                  acc, 0, 0, 0);
#pragma unroll
  for (int r = 0; r < 16; ++r) red[w][r][lane] = acc[r];
  __syncthreads();
  for (int s = threadIdx.x; s < 1024; s += 256) {
    int r = s >> 6, l = s & 63;
    float v = red[0][r][l] + red[1][r][l] + red[2][r][l] + red[3][r][l];
    int row = mt * 32 + (r & 3) + 8 * (r >> 2) + 4 * (l >> 5);
    int col = nt * 32 + (l & 31);
    out[(size_t)row * DMODEL + col] =
        v + b2[col] + x2[(size_t)row * DMODEL + col];
  }
}

// ---------------- launch -------------------------------------------------------------
extern "C" void kernel_launch(void* const* d_in, const int* in_sizes, int n_in,
                              void* d_out, int out_size, void* d_ws, size_t ws_size,
                              hipStream_t stream) {
  const float* x    = (const float*)d_in[0];
  const float* ln1g = (const float*)d_in[1];
  const float* ln1b = (const float*)d_in[2];
  const float* fcw  = (const float*)d_in[3];
  const float* fcb  = (const float*)d_in[4];
  const float* liw  = (const float*)d_in[5];
  const float* lib  = (const float*)d_in[6];
  const float* wa   = (const float*)d_in[7];
  const float* hidr = (const float*)d_in[8];
  const float* hidi = (const float*)d_in[9];
  const float* low  = (const float*)d_in[10];
  const float* lob  = (const float*)d_in[11];
  const float* ln2g = (const float*)d_in[12];
  const float* ln2b = (const float*)d_in[13];
  const float* w1   = (const float*)d_in[14];
  const float* b1   = (const float*)d_in[15];
  const float* w2   = (const float*)d_in[16];
  const float* b2   = (const float*)d_in[17];
  float* out = (float*)d_out;
  float* ws  = (float*)d_ws;

  float* y_   = ws;                            // 65536
  float* u_   = y_  + 65536;
  float* ar_  = u_  + 65536;
  float* ai_  = ar_ + 65536;
  float* h_   = ai_ + 65536;
  float* x2_  = h_  + 65536;                   // 524288
  u16* p = (u16*)(x2_ + 524288);
  u16* xnh  = p;            p += 524288;
  u16* xnl  = p;            p += 524288;
  u16* xn2s = p;            p += 524288;       // swizzled
  u16* h1s  = p;            p += 2097152;      // swizzled
  u16* w1s  = p;            p += 1048576;      // swizzled
  u16* w2s  = p;            p += 1048576;      // swizzled
  u16* fclh = p;            p += 65536;
  u16* fcll = p;            p += 65536;
  u16* wah  = p;            p += 8192;
  u16* wal  = p;            p += 8192;
  u16* lowh = p;            p += 32768;
  u16* lowl = p;            p += 32768;

  k_pre<<<2408, 256, 0, stream>>>(w1, w2, fcw, liw, wa, low, x, ln1g, ln1b,
                                  w1s, w2s, fclh, fcll, wah, wal, lowh, lowl,
                                  xnh, xnl);
  k_fa<<<64, 512, 0, stream>>>(xnh, xnl, fclh, fcll, wah, wal, fcb, lib,
                               y_, u_, ar_, ai_);
  k_scan2<<<128, 64, 0, stream>>>(u_, ar_, ai_, hidr, hidi, h_);
  k_midln<<<64, 1024, 0, stream>>>(h_, y_, lowh, lowl, lob, x, ln2g, ln2b,
                                   x2_, xn2s);
  k_ffn1<<<dim3(32, 16), 256, 0, stream>>>(xn2s, w1s, b1, h1s);
  k_ffn2<<<dim3(32, 16), 256, 0, stream>>>(h1s, w2s, b2, x2_, out);
}